// Round 8
// baseline (14050.723 us; speedup 1.0000x reference)
//
#include <hip/hip_runtime.h>
#include <hip/hip_bf16.h>

#define B_SZ 1024
#define T_ENC 384
#define T_DEC 128
#define I_SZ 128
#define H_SZ 512

typedef __attribute__((ext_vector_type(8))) short short8;
typedef __attribute__((ext_vector_type(4))) float floatx4;
typedef unsigned short ushort_t;
typedef unsigned long long u64;

__device__ __forceinline__ ushort_t f2bf(float x) {
    union { float f; unsigned int i; } v; v.f = x;
    unsigned int u = v.i;
    unsigned int r = (u + 0x7fffu + ((u >> 16) & 1u)) >> 16;
    return (ushort_t)r;
}
__device__ __forceinline__ float sigm(float x) { return 1.0f / (1.0f + __expf(-x)); }

// agent-coherent 8B load (bypasses possibly-stale per-XCD L2; served at coherence point)
__device__ __forceinline__ u64 ald8(const ushort_t* p) {
    return __hip_atomic_load((const u64*)(const void*)p, __ATOMIC_RELAXED, __HIP_MEMORY_SCOPE_AGENT);
}

// Bounded relaxed spin with fence fallback (hang-proof; fallback never fires when the
// relaxed-visibility model holds — validated rounds 4/7).
__device__ __forceinline__ void spin_ge(unsigned* p, unsigned tgt) {
    int n = 0;
    while (__hip_atomic_load(p, __ATOMIC_RELAXED, __HIP_MEMORY_SCOPE_AGENT) < tgt) {
        __builtin_amdgcn_s_sleep(2);
        if (++n == (1 << 13)) { __threadfence(); n = 0; }
    }
}

// Per-row-group monotone barrier: the h dependency is row-group-local (each block
// reads h rows [rg*64, rg*64+64) written only by same-rg blocks), so sync domains
// are 32 blocks (enc) / 16 blocks (dec) instead of the whole grid. Single line per
// rg: [count, signal]; relaxed AGENT atomics; no fences (L2 stays warm).
#define BLINE 64   // u32 per line (256B)
__device__ __forceinline__ void gbar_rg(unsigned* line, unsigned nb, unsigned& step) {
    asm volatile("s_waitcnt vmcnt(0) lgkmcnt(0)" ::: "memory");   // all waves: publish h
    __syncthreads();
    if (threadIdx.x == 0) {
        const unsigned s1 = step + 1;
        unsigned old = __hip_atomic_fetch_add(line, 1u, __ATOMIC_RELAXED, __HIP_MEMORY_SCOPE_AGENT);
        if (old == nb * s1 - 1u)
            __hip_atomic_store(line + 1, s1, __ATOMIC_RELAXED, __HIP_MEMORY_SCOPE_AGENT);
        else
            spin_ge(line + 1, s1);
    }
    step += 1;
    __syncthreads();
}

// fp32 -> bf16 bulk convert (weights, once per launch). n % 1024 == 0.
__global__ __launch_bounds__(256) void cvt_f32_bf16(
    const float* __restrict__ src, ushort_t* __restrict__ dst, int n)
{
    int i = (blockIdx.x * 256 + threadIdx.x) * 4;
    if (i < n) {
        float4 v = *(const float4*)(src + i);
        short4 s = { (short)f2bf(v.x), (short)f2bf(v.y), (short)f2bf(v.z), (short)f2bf(v.w) };
        *(short4*)(dst + i) = s;
    }
}

// dec_in(t=0) = bf16(x[:, -1, :])
__global__ void copy_last(const float* __restrict__ x, ushort_t* __restrict__ dst)
{
    int i = blockIdx.x * 256 + threadIdx.x;           // 0 .. 131071
    int b = i >> 7, k = i & 127;
    dst[i] = f2bf(x[((size_t)b * T_ENC + (T_ENC - 1)) * I_SZ + k]);
}

#define BM 64
#define BN 32
#define KC 64
#define LDSW (KC + 8)    // 72 shorts: 144B row stride, 16B-aligned
#define DLW  (I_SZ + 8)  // 136 shorts: DecIn stride

// XCD-aware swizzle: pin 2 col-groups per XCD so each XCD's weight slice (~832 KB)
// stays L2-resident across the persistent run.
__device__ __forceinline__ void tile_of(int bid, int& row0, int& col0) {
    int xcd = bid & 7, q = bid >> 3;          // q in [0,32)
    int cgp = xcd * 2 + (q & 1);              // col-group 0..15
    int rg = q >> 1;                          // row-group 0..15
    row0 = rg * BM; col0 = cgp * BN;
}

__device__ __forceinline__ void load_bias(
    const float* bih, const float* bhh, int col0, int l15, float (&bs)[4][2])
{
#pragma unroll
    for (int g = 0; g < 4; ++g)
#pragma unroll
        for (int n = 0; n < 2; ++n) {
            int gcol = col0 + n * 16 + l15;
            bs[g][n] = bih[g * H_SZ + gcol] + bhh[g * H_SZ + gcol];
        }
}

// One LSTM cell step for a 64row x (4 gates x 32)col tile; c and biases in registers.
// AMODE: 0 = A1 bf16 global h-buffer, 1 = A1 fp32 global x, 2 = A1 in LDS (DecIn).
// 2-deep register prefetch (E/O flat named reg sets, loop unrolled 2x — rule #20:
// no arrays/lambdas). Chunk k's regs are loaded at chunk k-2, giving two chunks of
// MFMA (~600cy) to cover L3 h-load latency (~600-900cy). Chunk counts per mode:
// AMODE0=16, AMODE1/2=10 (2 peeled + 8), fc=8 — all even.
template<int AMODE>
__device__ __forceinline__ void cell_step(
    int row0, int col0,
    const void* A1v, int lda1, int K1,
    const ushort_t* W1, const ushort_t* A2, const ushort_t* W2,
    const float (&bs)[4][2], float (&creg)[2][4],
    ushort_t* h_out, short* As, short* Ws)
{
    const int tid  = threadIdx.x;
    const int wave = tid >> 6;
    const int lane = tid & 63;
    const int quad = lane >> 4;
    const int l15  = lane & 15;
    const int sr   = tid >> 3;     // staging row 0..31 (+32 for second half)
    const int scch = tid & 7;      // staging 16B chunk

    floatx4 acc[4][2];
#pragma unroll
    for (int g = 0; g < 4; ++g)
#pragma unroll
        for (int n = 0; n < 2; ++n)
            acc[g][n] = (floatx4){0.f, 0.f, 0.f, 0.f};

    // flat named prefetch registers (E/O = even/odd chunk sets)
    u64 paE0 = 0, paE1 = 0, paE2 = 0, paE3 = 0;
    u64 paO0 = 0, paO1 = 0, paO2 = 0, paO3 = 0;
    int4 pwE0, pwE1, pwE2, pwE3, pwO0, pwO1, pwO2, pwO3;
    floatx4 px0 = {}, px1 = {}, px2 = {}, px3 = {};   // x chunk 0 (AMODE 1)
    floatx4 py0 = {}, py1 = {}, py2 = {}, py3 = {};   // x chunk 1 (AMODE 1)

    const int KT = K1 + H_SZ;

#define LDW_(kb_, w0, w1, w2, w3) do {                                             \
    const ushort_t* ws_; int wl_;                                                  \
    if ((kb_) < K1) { ws_ = W1 + (kb_);        wl_ = K1;  }                        \
    else            { ws_ = W2 + ((kb_) - K1); wl_ = H_SZ; }                       \
    w0 = *(const int4*)(const void*)(ws_ + (size_t)(0 * H_SZ + col0 + sr) * wl_ + scch * 8); \
    w1 = *(const int4*)(const void*)(ws_ + (size_t)(1 * H_SZ + col0 + sr) * wl_ + scch * 8); \
    w2 = *(const int4*)(const void*)(ws_ + (size_t)(2 * H_SZ + col0 + sr) * wl_ + scch * 8); \
    w3 = *(const int4*)(const void*)(ws_ + (size_t)(3 * H_SZ + col0 + sr) * wl_ + scch * 8); \
  } while (0)

#define LDA_(kb_, a0, a1, a2, a3) do {                                             \
    const ushort_t* ab_; int al_;                                                  \
    if ((kb_) < K1) { ab_ = (const ushort_t*)A1v + (kb_); al_ = lda1; }            \
    else            { ab_ = A2 + ((kb_) - K1);            al_ = H_SZ; }            \
    const ushort_t* s0_ = ab_ + (size_t)(row0 + sr)      * al_ + scch * 8;         \
    const ushort_t* s1_ = ab_ + (size_t)(row0 + sr + 32) * al_ + scch * 8;         \
    a0 = ald8(s0_); a1 = ald8(s0_ + 4);                                            \
    a2 = ald8(s1_); a3 = ald8(s1_ + 4);                                            \
  } while (0)

#define STA_(a0, a1, a2, a3) do {                                                  \
    u64* d0_ = (u64*)(void*)&As[sr * LDSW + scch * 8];                             \
    d0_[0] = a0; d0_[1] = a1;                                                      \
    u64* d1_ = (u64*)(void*)&As[(sr + 32) * LDSW + scch * 8];                      \
    d1_[0] = a2; d1_[1] = a3;                                                      \
  } while (0)

#define STW_(w0, w1, w2, w3) do {                                                  \
    *(int4*)(void*)&Ws[(0 * 32 + sr) * LDSW + scch * 8] = w0;                      \
    *(int4*)(void*)&Ws[(1 * 32 + sr) * LDSW + scch * 8] = w1;                      \
    *(int4*)(void*)&Ws[(2 * 32 + sr) * LDSW + scch * 8] = w2;                      \
    *(int4*)(void*)&Ws[(3 * 32 + sr) * LDSW + scch * 8] = w3;                      \
  } while (0)

#define STX_(p0, p1, p2, p3) do {                                                  \
    short4 s0_ = { (short)f2bf(p0.x), (short)f2bf(p0.y), (short)f2bf(p0.z), (short)f2bf(p0.w) }; \
    short4 s1_ = { (short)f2bf(p1.x), (short)f2bf(p1.y), (short)f2bf(p1.z), (short)f2bf(p1.w) }; \
    short4 s2_ = { (short)f2bf(p2.x), (short)f2bf(p2.y), (short)f2bf(p2.z), (short)f2bf(p2.w) }; \
    short4 s3_ = { (short)f2bf(p3.x), (short)f2bf(p3.y), (short)f2bf(p3.z), (short)f2bf(p3.w) }; \
    *(short4*)(void*)&As[((tid >> 4) +  0) * LDSW + (tid & 15) * 4] = s0_;         \
    *(short4*)(void*)&As[((tid >> 4) + 16) * LDSW + (tid & 15) * 4] = s1_;         \
    *(short4*)(void*)&As[((tid >> 4) + 32) * LDSW + (tid & 15) * 4] = s2_;         \
    *(short4*)(void*)&As[((tid >> 4) + 48) * LDSW + (tid & 15) * 4] = s3_;         \
  } while (0)

#define MFMA_(kb_) do {                                                            \
    _Pragma("unroll")                                                              \
    for (int ks_ = 0; ks_ < 2; ++ks_) {                                            \
        const int ko_ = ks_ * 32 + quad * 8;                                       \
        short8 a_;                                                                 \
        if (AMODE == 2 && (kb_) < K1)                                              \
            a_ = *(const short8*)(const void*)&((const short*)A1v)[(wave * 16 + l15) * DLW + (kb_) + ko_]; \
        else                                                                       \
            a_ = *(const short8*)(const void*)&As[(wave * 16 + l15) * LDSW + ko_]; \
        _Pragma("unroll")                                                          \
        for (int g_ = 0; g_ < 4; ++g_)                                             \
            _Pragma("unroll")                                                      \
            for (int n_ = 0; n_ < 2; ++n_) {                                       \
                short8 b_ = *(const short8*)(const void*)&Ws[(g_ * BN + n_ * 16 + l15) * LDSW + ko_]; \
                acc[g_][n_] = __builtin_amdgcn_mfma_f32_16x16x32_bf16(a_, b_, acc[g_][n_], 0, 0, 0); \
            }                                                                      \
    }                                                                              \
  } while (0)

    int kstart;
    if (AMODE == 0) {
        LDA_(0,  paE0, paE1, paE2, paE3);  LDW_(0,  pwE0, pwE1, pwE2, pwE3);
        LDA_(KC, paO0, paO1, paO2, paO3);  LDW_(KC, pwO0, pwO1, pwO2, pwO3);
        kstart = 0;
    } else {
        if (AMODE == 1) {
            const float* af_ = (const float*)A1v;
            px0 = *(const floatx4*)(const void*)(af_ + (size_t)(row0 + (tid >> 4) +  0) * lda1 + (tid & 15) * 4);
            px1 = *(const floatx4*)(const void*)(af_ + (size_t)(row0 + (tid >> 4) + 16) * lda1 + (tid & 15) * 4);
            px2 = *(const floatx4*)(const void*)(af_ + (size_t)(row0 + (tid >> 4) + 32) * lda1 + (tid & 15) * 4);
            px3 = *(const floatx4*)(const void*)(af_ + (size_t)(row0 + (tid >> 4) + 48) * lda1 + (tid & 15) * 4);
            const float* ag_ = af_ + KC;
            py0 = *(const floatx4*)(const void*)(ag_ + (size_t)(row0 + (tid >> 4) +  0) * lda1 + (tid & 15) * 4);
            py1 = *(const floatx4*)(const void*)(ag_ + (size_t)(row0 + (tid >> 4) + 16) * lda1 + (tid & 15) * 4);
            py2 = *(const floatx4*)(const void*)(ag_ + (size_t)(row0 + (tid >> 4) + 32) * lda1 + (tid & 15) * 4);
            py3 = *(const floatx4*)(const void*)(ag_ + (size_t)(row0 + (tid >> 4) + 48) * lda1 + (tid & 15) * 4);
        }
        LDW_(0,  pwE0, pwE1, pwE2, pwE3);
        LDW_(KC, pwO0, pwO1, pwO2, pwO3);
        // peel chunk 0
        if (AMODE == 1) STX_(px0, px1, px2, px3);
        STW_(pwE0, pwE1, pwE2, pwE3);
        __syncthreads();
        LDA_(2 * KC, paE0, paE1, paE2, paE3);  LDW_(2 * KC, pwE0, pwE1, pwE2, pwE3);
        MFMA_(0);
        __syncthreads();
        // peel chunk 1
        if (AMODE == 1) STX_(py0, py1, py2, py3);
        STW_(pwO0, pwO1, pwO2, pwO3);
        __syncthreads();
        LDA_(3 * KC, paO0, paO1, paO2, paO3);  LDW_(3 * KC, pwO0, pwO1, pwO2, pwO3);
        MFMA_(KC);
        __syncthreads();
        kstart = 2 * KC;
    }

    for (int kb = kstart; kb < KT; kb += 2 * KC) {
        // even chunk
        STA_(paE0, paE1, paE2, paE3);  STW_(pwE0, pwE1, pwE2, pwE3);
        __syncthreads();
        {
            const int kn_ = kb + 2 * KC;
            if (kn_ < KT) { LDA_(kn_, paE0, paE1, paE2, paE3); LDW_(kn_, pwE0, pwE1, pwE2, pwE3); }
        }
        MFMA_(kb);
        __syncthreads();
        // odd chunk
        STA_(paO0, paO1, paO2, paO3);  STW_(pwO0, pwO1, pwO2, pwO3);
        __syncthreads();
        {
            const int kn_ = kb + 3 * KC;
            if (kn_ < KT) { LDA_(kn_, paO0, paO1, paO2, paO3); LDW_(kn_, pwO0, pwO1, pwO2, pwO3); }
        }
        MFMA_(kb + KC);
        __syncthreads();
    }

#undef LDW_
#undef LDA_
#undef STA_
#undef STW_
#undef STX_
#undef MFMA_

#pragma unroll
    for (int n = 0; n < 2; ++n) {
        const int gcol = col0 + n * 16 + l15;
#pragma unroll
        for (int r = 0; r < 4; ++r) {
            const int grow = row0 + wave * 16 + quad * 4 + r;
            const float zi = acc[0][n][r] + bs[0][n];
            const float zf = acc[1][n][r] + bs[1][n];
            const float zg = acc[2][n][r] + bs[2][n];
            const float zo = acc[3][n][r] + bs[3][n];
            const float cn = sigm(zf) * creg[n][r] + sigm(zi) * tanhf(zg);
            creg[n][r] = cn;
            const float hv = sigm(zo) * tanhf(cn);
            const float hnb = __shfl_xor(hv, 1);
            if ((lane & 1) == 0) {   // paired lanes: one 32-bit agent store per 2 cols
                unsigned p = (unsigned)f2bf(hv) | ((unsigned)f2bf(hnb) << 16);
                __hip_atomic_store((unsigned*)(void*)&h_out[(size_t)grow * H_SZ + gcol],
                                   p, __ATOMIC_RELAXED, __HIP_MEMORY_SCOPE_AGENT);
            }
        }
    }
}

// Persistent encoder: 512 blocks (2/CU, all resident).
// Blocks 0..255: L0(t) for t=0..383.  Blocks 256..511: L1(t-1) for t=1..384.
// Per-rg barrier: 32 blocks (16 L0 + 16 L1 col-group siblings) per domain.
__global__ __launch_bounds__(256, 2) void enc_persist(
    const float* x,
    const ushort_t* Wih0, const ushort_t* Whh0, const float* bih0, const float* bhh0,
    const ushort_t* Wih1, const ushort_t* Whh1, const float* bih1, const float* bhh1,
    ushort_t* h0a, ushort_t* h0b, ushort_t* h1a, ushort_t* h1b,
    float* c0, float* c1, unsigned* bar)
{
    __shared__ short As[BM * LDSW];
    __shared__ short Ws[4 * BN * LDSW];

    const int tid = threadIdx.x;
    const int bid = blockIdx.x;
    const bool isL0 = (bid < 256);
    int row0, col0; tile_of(isL0 ? bid : (bid - 256), row0, col0);
    const int lane = tid & 63, l15 = lane & 15, quad = lane >> 4, wave = tid >> 6;
    unsigned* bline = bar + (size_t)(row0 >> 6) * BLINE;

    float bs[4][2];
    load_bias(isL0 ? bih0 : bih1, isL0 ? bhh0 : bhh1, col0, l15, bs);
    float creg[2][4];
#pragma unroll
    for (int n = 0; n < 2; ++n)
#pragma unroll
        for (int r = 0; r < 4; ++r) creg[n][r] = 0.f;

    ushort_t *h0c = h0a, *h0n = h0b, *h1c = h1a, *h1n = h1b;
    unsigned step = 0;

    for (int t = 0; t <= T_ENC; ++t) {
        if (isL0) {
            if (t < T_ENC)
                cell_step<1>(row0, col0, x + (size_t)t * I_SZ, T_ENC * I_SZ, I_SZ,
                             Wih0, h0c, Whh0, bs, creg, h0n, As, Ws);
        } else {
            if (t > 0)
                cell_step<0>(row0, col0, h0c, H_SZ, H_SZ,
                             Wih1, h1c, Whh1, bs, creg, h1n, As, Ws);
        }
        gbar_rg(bline, 32, step);
        if (t < T_ENC) { ushort_t* tmp = h0c; h0c = h0n; h0n = tmp; }
        if (t > 0)     { ushort_t* tmp = h1c; h1c = h1n; h1n = tmp; }
    }
    // final c states for the decoder (kernel boundary publishes them)
    float* cdst = isL0 ? c0 : c1;
#pragma unroll
    for (int n = 0; n < 2; ++n)
#pragma unroll
        for (int r = 0; r < 4; ++r) {
            int grow = row0 + wave * 16 + quad * 4 + r;
            int gcol = col0 + n * 16 + l15;
            cdst[(size_t)grow * H_SZ + gcol] = creg[n][r];
        }
}

// Persistent decoder: 256 blocks (all resident). Each block owns the same (rg,cg)
// tile of BOTH layers; c0/c1 tiles live in registers the whole run.
// Per step t: [fc(t-1)+out + L0(t)]  rg-barrier(16)  [L1(t)]  rg-barrier(16).
__global__ __launch_bounds__(256, 2) void dec_persist(
    const ushort_t* dec0, const ushort_t* fcw, const float* fcb, float* out,
    const ushort_t* Wih0, const ushort_t* Whh0, const float* bih0, const float* bhh0,
    const ushort_t* Wih1, const ushort_t* Whh1, const float* bih1, const float* bhh1,
    ushort_t* h0a, ushort_t* h0b, ushort_t* h1a, ushort_t* h1b,
    const float* c0in, const float* c1in, unsigned* bar)
{
    __shared__ short As[BM * LDSW];
    __shared__ short Ws[4 * BN * LDSW];
    __shared__ short DecIn[BM * DLW];

    const int tid = threadIdx.x;
    const int wave = tid >> 6, lane = tid & 63, quad = lane >> 4, l15 = lane & 15;
    const int sr = tid >> 3, scch = tid & 7;
    int row0, col0; tile_of(blockIdx.x, row0, col0);
    const int cgrp = col0 / BN;
    unsigned* bline = bar + (size_t)(row0 >> 6) * BLINE;

    float bs0[4][2], bs1[4][2];
    load_bias(bih0, bhh0, col0, l15, bs0);
    load_bias(bih1, bhh1, col0, l15, bs1);

    float c0reg[2][4], c1reg[2][4];
#pragma unroll
    for (int n = 0; n < 2; ++n)
#pragma unroll
        for (int r = 0; r < 4; ++r) {
            int grow = row0 + wave * 16 + quad * 4 + r;
            int gcol = col0 + n * 16 + l15;
            c0reg[n][r] = c0in[(size_t)grow * H_SZ + gcol];
            c1reg[n][r] = c1in[(size_t)grow * H_SZ + gcol];
        }

    ushort_t *h0c = h0a, *h0n = h0b, *h1c = h1a, *h1n = h1b;
    unsigned step = 0;

    for (int t = 0; t <= T_DEC; ++t) {
        // ---------- phase A: fc(t-1) -> DecIn (+ out(t-1)), then L0(t) ----------
        if (t > 0) {
            float* outp = out + (size_t)(t - 1) * I_SZ;
            floatx4 a2[8];
#pragma unroll
            for (int n = 0; n < 8; ++n) a2[n] = (floatx4){0.f, 0.f, 0.f, 0.f};

            u64 faE0, faE1, faE2, faE3, faO0, faO1, faO2, faO3;
            int4 fwE0, fwE1, fwE2, fwE3, fwO0, fwO1, fwO2, fwO3;
#define LDFA_(kb_, a0, a1, a2_, a3_) do {                                          \
    const ushort_t* s0_ = h1c + (size_t)(row0 + sr)      * H_SZ + (kb_) + scch * 8; \
    const ushort_t* s1_ = h1c + (size_t)(row0 + sr + 32) * H_SZ + (kb_) + scch * 8; \
    a0 = ald8(s0_); a1 = ald8(s0_ + 4);                                            \
    a2_ = ald8(s1_); a3_ = ald8(s1_ + 4);                                          \
  } while (0)
#define LDFW_(kb_, w0, w1, w2, w3) do {                                            \
    w0 = *(const int4*)(const void*)(fcw + (size_t)(0 * 32 + sr) * H_SZ + (kb_) + scch * 8); \
    w1 = *(const int4*)(const void*)(fcw + (size_t)(1 * 32 + sr) * H_SZ + (kb_) + scch * 8); \
    w2 = *(const int4*)(const void*)(fcw + (size_t)(2 * 32 + sr) * H_SZ + (kb_) + scch * 8); \
    w3 = *(const int4*)(const void*)(fcw + (size_t)(3 * 32 + sr) * H_SZ + (kb_) + scch * 8); \
  } while (0)
#define STFA_(a0, a1, a2_, a3_) do {                                               \
    u64* d0_ = (u64*)(void*)&As[sr * LDSW + scch * 8];                             \
    d0_[0] = a0; d0_[1] = a1;                                                      \
    u64* d1_ = (u64*)(void*)&As[(sr + 32) * LDSW + scch * 8];                      \
    d1_[0] = a2_; d1_[1] = a3_;                                                    \
  } while (0)
#define STFW_(w0, w1, w2, w3) do {                                                 \
    *(int4*)(void*)&Ws[(0 * 32 + sr) * LDSW + scch * 8] = w0;                      \
    *(int4*)(void*)&Ws[(1 * 32 + sr) * LDSW + scch * 8] = w1;                      \
    *(int4*)(void*)&Ws[(2 * 32 + sr) * LDSW + scch * 8] = w2;                      \
    *(int4*)(void*)&Ws[(3 * 32 + sr) * LDSW + scch * 8] = w3;                      \
  } while (0)
#define FCMFMA_() do {                                                             \
    _Pragma("unroll")                                                              \
    for (int ks_ = 0; ks_ < 2; ++ks_) {                                            \
        const int ko_ = ks_ * 32 + quad * 8;                                       \
        short8 a_ = *(const short8*)(const void*)&As[(wave * 16 + l15) * LDSW + ko_]; \
        _Pragma("unroll")                                                          \
        for (int n_ = 0; n_ < 8; ++n_) {                                           \
            short8 b_ = *(const short8*)(const void*)&Ws[(n_ * 16 + l15) * LDSW + ko_]; \
            a2[n_] = __builtin_amdgcn_mfma_f32_16x16x32_bf16(a_, b_, a2[n_], 0, 0, 0); \
        }                                                                          \
    }                                                                              \
  } while (0)
            LDFA_(0,  faE0, faE1, faE2, faE3);  LDFW_(0,  fwE0, fwE1, fwE2, fwE3);
            LDFA_(KC, faO0, faO1, faO2, faO3);  LDFW_(KC, fwO0, fwO1, fwO2, fwO3);

            for (int kb = 0; kb < H_SZ; kb += 2 * KC) {
                STFA_(faE0, faE1, faE2, faE3);  STFW_(fwE0, fwE1, fwE2, fwE3);
                __syncthreads();
                {
                    const int kn_ = kb + 2 * KC;
                    if (kn_ < H_SZ) { LDFA_(kn_, faE0, faE1, faE2, faE3); LDFW_(kn_, fwE0, fwE1, fwE2, fwE3); }
                }
                FCMFMA_();
                __syncthreads();
                STFA_(faO0, faO1, faO2, faO3);  STFW_(fwO0, fwO1, fwO2, fwO3);
                __syncthreads();
                {
                    const int kn_ = kb + 3 * KC;
                    if (kn_ < H_SZ) { LDFA_(kn_, faO0, faO1, faO2, faO3); LDFW_(kn_, fwO0, fwO1, fwO2, fwO3); }
                }
                FCMFMA_();
                __syncthreads();
            }
#undef LDFA_
#undef LDFW_
#undef STFA_
#undef STFW_
#undef FCMFMA_
#pragma unroll
            for (int n = 0; n < 8; ++n) {
                const int col = n * 16 + l15;
                const float bias = fcb[col];
#pragma unroll
                for (int r = 0; r < 4; ++r) {
                    const int lrow = wave * 16 + quad * 4 + r;
                    const float v = a2[n][r] + bias;
                    DecIn[lrow * DLW + col] = (short)f2bf(v);
                    if (cgrp == 0)
                        outp[(size_t)(row0 + lrow) * T_DEC * I_SZ + col] = v;
                }
            }
        } else {
            // t==0: dec_in from global bf16 buffer (written by an earlier dispatch)
#pragma unroll
            for (int it = 0; it < 4; ++it) {
                int idx = tid + it * 256;              // 0..1023
                int r = idx >> 4, cch = idx & 15;
                int4 v = *(const int4*)(const void*)(dec0 + (size_t)(row0 + r) * I_SZ + cch * 8);
                *(int4*)(void*)&DecIn[r * DLW + cch * 8] = v;
            }
        }
        __syncthreads();

        if (t < T_DEC)
            cell_step<2>(row0, col0, (const void*)DecIn, DLW, I_SZ,
                         Wih0, h0c, Whh0, bs0, c0reg, h0n, As, Ws);
        gbar_rg(bline, 16, step);

        // ---------- phase B: L1(t) ----------
        if (t < T_DEC) {
            cell_step<0>(row0, col0, h0n, H_SZ, H_SZ,
                         Wih1, h1c, Whh1, bs1, c1reg, h1n, As, Ws);
            gbar_rg(bline, 16, step);
            { ushort_t* tmp = h0c; h0c = h0n; h0n = tmp; }
            { ushort_t* tmp = h1c; h1c = h1n; h1n = tmp; }
        }
    }
}

extern "C" void kernel_launch(void* const* d_in, const int* in_sizes, int n_in,
                              void* d_out, int out_size, void* d_ws, size_t ws_size,
                              hipStream_t stream)
{
    (void)in_sizes; (void)n_in; (void)out_size; (void)ws_size;
    const float* x     = (const float*)d_in[0];
    const float* W_ih0 = (const float*)d_in[1];
    const float* W_hh0 = (const float*)d_in[2];
    const float* b_ih0 = (const float*)d_in[3];
    const float* b_hh0 = (const float*)d_in[4];
    const float* W_ih1 = (const float*)d_in[5];
    const float* W_hh1 = (const float*)d_in[6];
    const float* b_ih1 = (const float*)d_in[7];
    const float* b_hh1 = (const float*)d_in[8];
    const float* fc_w  = (const float*)d_in[9];
    const float* fc_b  = (const float*)d_in[10];
    float* out = (float*)d_out;

    const int NW_IH0 = 4 * H_SZ * I_SZ;   // 262144
    const int NW_HH  = 4 * H_SZ * H_SZ;   // 1048576
    const int NW_FC  = I_SZ * H_SZ;       // 65536
    char* w = (char*)d_ws;
    ushort_t* wb_ih0 = (ushort_t*)w;  w += (size_t)NW_IH0 * 2;
    ushort_t* wb_hh0 = (ushort_t*)w;  w += (size_t)NW_HH  * 2;
    ushort_t* wb_ih1 = (ushort_t*)w;  w += (size_t)NW_HH  * 2;
    ushort_t* wb_hh1 = (ushort_t*)w;  w += (size_t)NW_HH  * 2;
    ushort_t* wb_fc  = (ushort_t*)w;  w += (size_t)NW_FC  * 2;
    const size_t HB2 = (size_t)B_SZ * H_SZ * 2;    // 1 MB bf16
    const size_t HB4 = (size_t)B_SZ * H_SZ * 4;    // 2 MB fp32
    ushort_t* h0a = (ushort_t*)w;  w += HB2;
    ushort_t* h0b = (ushort_t*)w;  w += HB2;
    ushort_t* h1a = (ushort_t*)w;  w += HB2;
    ushort_t* h1b = (ushort_t*)w;  w += HB2;
    float*    c0  = (float*)w;     w += HB4;
    float*    c1  = (float*)w;     w += HB4;
    ushort_t* dec0 = (ushort_t*)w; w += (size_t)B_SZ * I_SZ * 2;
    // per-rg barrier lines: enc 16 lines, dec 16 lines (256B each)
    unsigned* bar_enc = (unsigned*)w;              // 16 * 256B
    unsigned* bar_dec = bar_enc + 16 * BLINE;      // 16 * 256B
    const size_t BAR_BYTES = 32 * 256;
    w += BAR_BYTES;

    cvt_f32_bf16<<<NW_IH0 / 1024, 256, 0, stream>>>(W_ih0, wb_ih0, NW_IH0);
    cvt_f32_bf16<<<NW_HH  / 1024, 256, 0, stream>>>(W_hh0, wb_hh0, NW_HH);
    cvt_f32_bf16<<<NW_HH  / 1024, 256, 0, stream>>>(W_ih1, wb_ih1, NW_HH);
    cvt_f32_bf16<<<NW_HH  / 1024, 256, 0, stream>>>(W_hh1, wb_hh1, NW_HH);
    cvt_f32_bf16<<<NW_FC  / 1024, 256, 0, stream>>>(fc_w,  wb_fc,  NW_FC);

    hipMemsetAsync(h0a, 0, HB2, stream);
    hipMemsetAsync(h1a, 0, HB2, stream);
    hipMemsetAsync(bar_enc, 0, BAR_BYTES, stream);
    copy_last<<<512, 256, 0, stream>>>(x, dec0);

    // whole encoder: ONE launch, per-rg barriers between steps
    enc_persist<<<512, 256, 0, stream>>>(
        x, wb_ih0, wb_hh0, b_ih0, b_hh0,
        wb_ih1, wb_hh1, b_ih1, b_hh1,
        h0a, h0b, h1a, h1b, c0, c1, bar_enc);

    // whole decoder (incl. final fc): ONE launch
    dec_persist<<<256, 256, 0, stream>>>(
        dec0, wb_fc, fc_b, out,
        wb_ih0, wb_hh0, b_ih0, b_hh0,
        wb_ih1, wb_hh1, b_ih1, b_hh1,
        h0a, h0b, h1a, h1b, c0, c1, bar_dec);
}